// Round 9
// baseline (50.518 us; speedup 1.0000x reference)
//
#include <hip/hip_runtime.h>
#include <hip/hip_bf16.h>

// ---------------------------------------------------------------------------
// TT-adapter fused kernel for MI355X (gfx950)
// out = hs + gelu(hs @ W_down + b_down) @ W_up + b_up
// W_down [768,64], W_up [64,768] reconstructed from rank-5 TT cores.
//
// Kernel 0: build bf16 weights in MFMA-fragment-ready layout in d_ws.
// Kernel 1: PERSISTENT pipelined kernel. 256 blocks x 512 thr (8 waves),
//   one block per CU, 16 tiles of 8 rows per block, 2x24KB LDS double buffer:
//   DMA(tile t+1) issued before compute(tile t); counted vmcnt; raw s_barrier
//   (never __syncthreads -> would drain vmcnt and kill the pipeline).
//   All weights preloaded to VGPR: ZERO global->VGPR loads inside the loop,
//   so vmcnt counting is exact. Store completion off the critical path.
// ---------------------------------------------------------------------------

typedef __attribute__((ext_vector_type(8))) short bf16x8;
typedef __attribute__((ext_vector_type(4))) float f32x4;

__device__ __forceinline__ unsigned short f2bf(float f) {
    union { float f; unsigned u; } v; v.f = f;
    unsigned r = (v.u + 0x7FFFu + ((v.u >> 16) & 1u)) >> 16;
    return (unsigned short)r;
}

// Staged TT contraction for one matrix entry (cores in LDS).
__device__ __forceinline__ float tt_entry(
    const float* c0, const float* c1, const float* c2,
    const float* c3, const float* c4,
    int i0, int i1, int i2, int i3, int i4)
{
    float v1[5], v2[5], v3[5];
#pragma unroll
    for (int r2 = 0; r2 < 5; ++r2) {
        float s = 0.f;
#pragma unroll
        for (int r1 = 0; r1 < 5; ++r1)
            s += c0[i0 * 5 + r1] * c1[(r1 * 8 + i1) * 5 + r2];
        v1[r2] = s;
    }
#pragma unroll
    for (int r3 = 0; r3 < 5; ++r3) {
        float s = 0.f;
#pragma unroll
        for (int r2 = 0; r2 < 5; ++r2)
            s += v1[r2] * c2[(r2 * 12 + i2) * 5 + r3];
        v2[r3] = s;
    }
#pragma unroll
    for (int r4 = 0; r4 < 5; ++r4) {
        float s = 0.f;
#pragma unroll
        for (int r3 = 0; r3 < 5; ++r3)
            s += v2[r3] * c3[(r3 * 8 + i3) * 5 + r4];
        v3[r4] = s;
    }
    float w = 0.f;
#pragma unroll
    for (int r4 = 0; r4 < 5; ++r4)
        w += v3[r4] * c4[r4 * 8 + i4];
    return w;
}

// WdFrag[((ks*4+nt)*64 + lane)*8 + j] = Wd[ks*32 + (lane>>4)*8 + j][nt*16 + (lane&15)]
// WuFrag[((s*48+ht)*64 + lane)*8 + j] = Wu[s*32  + (lane>>4)*8 + j][ht*16 + (lane&15)]
//   (B-frag of Wu == A-frag of Wu^T, so the same buffer serves the swapped GEMM)
__global__ __launch_bounds__(256) void tt_build_frags(
    const float* __restrict__ d0, const float* __restrict__ d1,
    const float* __restrict__ d2, const float* __restrict__ d3,
    const float* __restrict__ d4,
    const float* __restrict__ u0, const float* __restrict__ u1,
    const float* __restrict__ u2, const float* __restrict__ u3,
    const float* __restrict__ u4,
    unsigned short* __restrict__ wdFrag, unsigned short* __restrict__ wuFrag)
{
    __shared__ float cs[1560];
    {
        const float* srcs[10] = { d0, d1, d2, d3, d4, u0, u1, u2, u3, u4 };
        const int sizes[10]   = { 40, 200, 300, 200, 40, 40, 200, 300, 200, 40 };
        const int offs[10]    = { 0, 40, 240, 540, 740, 780, 820, 1020, 1320, 1520 };
#pragma unroll
        for (int c = 0; c < 10; ++c)
            for (int i = threadIdx.x; i < sizes[c]; i += 256)
                cs[offs[c] + i] = srcs[c][i];
    }
    __syncthreads();

    int e = blockIdx.x * 256 + threadIdx.x;   // 0..98303
    bool isUp = (e >= 49152);
    int idx = isUp ? (e - 49152) : e;
    int j    = idx & 7;
    int lane = (idx >> 3) & 63;
    int tile = idx >> 9;                      // 0..95
    int kg = lane >> 4, ln = lane & 15;

    if (!isUp) {
        int ks = tile >> 2, nt = tile & 3;
        int k = ks * 32 + kg * 8 + j;
        int a = nt * 16 + ln;
        int i0 = k / 96, i1 = (k / 12) % 8, i2 = k % 12;
        int i3 = a >> 3, i4 = a & 7;
        float w = tt_entry(cs + 0, cs + 40, cs + 240, cs + 540, cs + 740,
                           i0, i1, i2, i3, i4);
        wdFrag[idx] = f2bf(w);
    } else {
        int s = tile / 48, ht = tile % 48;
        int aIn = s * 32 + kg * 8 + j;
        int h = ht * 16 + ln;
        int i0 = aIn >> 3, i1 = aIn & 7;
        int i2 = h / 64, i3 = (h >> 3) & 7, i4 = h & 7;
        float w = tt_entry(cs + 780, cs + 820, cs + 1020, cs + 1320, cs + 1520,
                           i0, i1, i2, i3, i4);
        wuFrag[idx] = f2bf(w);
    }
}

__device__ __forceinline__ bf16x8 cvt8(f32x4 a, f32x4 b) {
    union { bf16x8 v; __hip_bfloat162 h[4]; } r;
    r.h[0] = __float22bfloat162_rn(make_float2(a[0], a[1]));
    r.h[1] = __float22bfloat162_rn(make_float2(a[2], a[3]));
    r.h[2] = __float22bfloat162_rn(make_float2(b[0], b[1]));
    r.h[3] = __float22bfloat162_rn(make_float2(b[2], b[3]));
    return r.v;
}

// ---------------------------------------------------------------------------
// Persistent pipelined kernel.
// Tile = 8 rows x 768 f32 = 24KB. buf layout: [8 rows][3072 B], byte col cb of
// row r lives at r*3072 + (cb ^ (r<<4)) (16B-granular involution, bits 4-6).
// DMA source carries the same XOR; DMA dest is linear (wave-uniform+lane*16).
//
// Wave roles (w = 0..7):
//   p1 (down): kh = w&3 (K quarter, 6 ks), ntp = w>>2 (2 nt cols) -> 12 MFMA.
//   reduce+gelu: all 512 threads, one (row,col) each.
//   p2 (up, swapped): 6 ht tiles per wave; in-place residual rmw (ln<8).
//   store: wave w stores row w (3 x 1KB full-line stores).
//
// vmcnt discipline (in-order retirement): per lane 3 DMA + 3 stores per tile.
// At iter-t wait: older=DMA(t); younger=stores(t-1):3 + DMA(t+1):3 -> vmcnt(6).
// t==0 / t==15: only 3 younger -> vmcnt(3).
// ---------------------------------------------------------------------------
__global__ __launch_bounds__(512, 2) void adapter_fused(
    const float* __restrict__ hs,
    const float* __restrict__ b_down,
    const float* __restrict__ b_up,
    const unsigned short* __restrict__ wdFrag,
    const unsigned short* __restrict__ wuFrag,
    float* __restrict__ out)
{
    __shared__ char  bufs[2][24576];
    __shared__ float part[4][8][68];
    __shared__ char  act_s[1024];

    const int tid  = threadIdx.x;
    const int lane = tid & 63;
    const int w    = tid >> 6;     // 0..7
    const int ln   = lane & 15;
    const int kg   = lane >> 4;
    const int kh   = w & 3;        // p1 K-quarter
    const int ntp  = w >> 2;       // p1 nt pair
    const int arow = ln & 7;       // A row (dup for ln>=8; outputs ignored)

    // ---- tile-invariant register preloads (NO global loads inside loop) ----
    const float bdv = b_down[tid & 63];
    bf16x8 wd[12];
#pragma unroll
    for (int ks = 0; ks < 6; ++ks)
#pragma unroll
        for (int s = 0; s < 2; ++s)
            wd[ks * 2 + s] = *(const bf16x8*)(
                wdFrag + ((kh * 6 + ks) * 4 + (ntp * 2 + s)) * 512 + lane * 8);
    bf16x8 wu[12];
    f32x4  buv[6];
#pragma unroll
    for (int n2 = 0; n2 < 6; ++n2) {
        const int ht = w * 6 + n2;
#pragma unroll
        for (int s = 0; s < 2; ++s)
            wu[n2 * 2 + s] = *(const bf16x8*)(
                wuFrag + (s * 48 + ht) * 512 + lane * 8);
        buv[n2] = *(const f32x4*)(b_up + ht * 16 + kg * 4);
    }

    // ---- tile-invariant DMA offsets (3 chunks of 16B per lane) ----
    unsigned dst_off[3], src_off[3];
#pragma unroll
    for (int i = 0; i < 3; ++i) {
        unsigned dl  = (unsigned)(i * 8192 + tid * 16);
        unsigned row = dl / 3072u;
        unsigned cb  = dl - row * 3072u;
        dst_off[i] = dl;
        src_off[i] = row * 3072u + (cb ^ (row << 4));
    }

    const size_t grow0 = (size_t)blockIdx.x * 128;   // 16 tiles x 8 rows

    // ---- prologue: stage tile 0 into buf 0 ----
    {
        const char* g = (const char*)hs + grow0 * 3072;
#pragma unroll
        for (int i = 0; i < 3; ++i)
            __builtin_amdgcn_global_load_lds(
                (const __attribute__((address_space(1))) unsigned int*)(g + src_off[i]),
                (__attribute__((address_space(3))) unsigned int*)(&bufs[0][0] + dst_off[i]),
                16, 0, 0);
    }

    for (int t = 0; t < 16; ++t) {
        char* buf = &bufs[t & 1][0];

        // B1: all waves done issuing tile(t-1) stores (their LDS reads retired)
        asm volatile("s_barrier" ::: "memory");

        if (t < 15) {   // issue DMA for tile t+1 into the other buffer
            const char* g = (const char*)hs + (grow0 + (size_t)(t + 1) * 8) * 3072;
            char* nbuf = &bufs[(t + 1) & 1][0];
#pragma unroll
            for (int i = 0; i < 3; ++i)
                __builtin_amdgcn_global_load_lds(
                    (const __attribute__((address_space(1))) unsigned int*)(g + src_off[i]),
                    (__attribute__((address_space(3))) unsigned int*)(nbuf + dst_off[i]),
                    16, 0, 0);
        }

        // wait for tile-t DMA (counted; stores(t-1)+DMA(t+1) stay in flight)
        if (t == 0 || t == 15)
            asm volatile("s_waitcnt vmcnt(3)\n\ts_barrier" ::: "memory");
        else
            asm volatile("s_waitcnt vmcnt(6)\n\ts_barrier" ::: "memory");
        __builtin_amdgcn_sched_barrier(0);

        // ---------------- p1: down GEMM, 8-way split ----------------
        f32x4 acc0 = (f32x4){0.f, 0.f, 0.f, 0.f};
        f32x4 acc1 = (f32x4){0.f, 0.f, 0.f, 0.f};
        {
            const unsigned rb = (unsigned)(arow * 3072);
            const unsigned sz = (unsigned)(arow << 4);
#pragma unroll
            for (int ks = 0; ks < 6; ++ks) {
                unsigned c0 = (unsigned)(kh * 768 + ks * 128 + kg * 32);
                f32x4 fa = *(const f32x4*)(buf + rb + ((c0) ^ sz));
                f32x4 fb = *(const f32x4*)(buf + rb + ((c0 + 16u) ^ sz));
                bf16x8 af = cvt8(fa, fb);
                acc0 = __builtin_amdgcn_mfma_f32_16x16x32_bf16(af, wd[ks*2+0], acc0, 0, 0, 0);
                acc1 = __builtin_amdgcn_mfma_f32_16x16x32_bf16(af, wd[ks*2+1], acc1, 0, 0, 0);
            }
        }
        if (kg < 2) {   // valid D rows are 0..7 (kg*4+r)
#pragma unroll
            for (int r = 0; r < 4; ++r) {
                part[kh][kg * 4 + r][ntp * 32 + ln]      = acc0[r];
                part[kh][kg * 4 + r][ntp * 32 + 16 + ln] = acc1[r];
            }
        }
        asm volatile("s_waitcnt lgkmcnt(0)\n\ts_barrier" ::: "memory");

        // ---------------- reduce + bias + exact gelu -> act ----------------
        {
            const int r = tid >> 6, c = tid & 63;
            float x = part[0][r][c] + part[1][r][c] + part[2][r][c]
                    + part[3][r][c] + bdv;
            float g = 0.5f * x * (1.0f + erff(x * 0.70710678118654752f));
            *(unsigned short*)(act_s + ((unsigned)(r * 128 + c * 2)
                                        ^ ((unsigned)r << 4))) = f2bf(g);
        }
        asm volatile("s_waitcnt lgkmcnt(0)\n\ts_barrier" ::: "memory");

        // ---------------- p2: up GEMM (swapped) + in-place residual --------
        bf16x8 pa0, pa1;
        {
            const unsigned sz = (unsigned)(arow << 4);
            pa0 = *(const bf16x8*)(act_s + ((unsigned)(arow * 128 + kg * 16) ^ sz));
            pa1 = *(const bf16x8*)(act_s + ((unsigned)(arow * 128 + 64 + kg * 16) ^ sz));
        }
#pragma unroll
        for (int n2 = 0; n2 < 6; ++n2) {
            const int ht = w * 6 + n2;
            f32x4 a2 = (f32x4){0.f, 0.f, 0.f, 0.f};
            a2 = __builtin_amdgcn_mfma_f32_16x16x32_bf16(wu[n2*2+0], pa0, a2, 0, 0, 0);
            a2 = __builtin_amdgcn_mfma_f32_16x16x32_bf16(wu[n2*2+1], pa1, a2, 0, 0, 0);
            if (ln < 8) {   // D col n = ln = tile row; rows 8..15 are garbage
                unsigned off = (unsigned)(ln * 3072)
                             + ((unsigned)(ht * 64 + kg * 16) ^ ((unsigned)ln << 4));
                f32x4 hv = *(const f32x4*)(buf + off);
                f32x4 o;
#pragma unroll
                for (int j = 0; j < 4; ++j) o[j] = a2[j] + hv[j] + buv[n2][j];
                *(f32x4*)(buf + off) = o;
            }
        }
        asm volatile("s_waitcnt lgkmcnt(0)\n\ts_barrier" ::: "memory");

        // ---------------- bulk store: wave w stores row w (full lines) -----
        {
            char* og = (char*)out + (grow0 + (size_t)t * 8 + w) * 3072;
            const unsigned rb = (unsigned)(w * 3072);
            const unsigned sz = (unsigned)(w << 4);
#pragma unroll
            for (int i = 0; i < 3; ++i) {
                unsigned colb = (unsigned)(i * 1024 + lane * 16);
                f32x4 v = *(const f32x4*)(buf + rb + (colb ^ sz));
                *(f32x4*)(og + colb) = v;
            }
        }
    }
}

extern "C" void kernel_launch(void* const* d_in, const int* in_sizes, int n_in,
                              void* d_out, int out_size, void* d_ws, size_t ws_size,
                              hipStream_t stream) {
    // dict order: hidden_states, b_down, b_up, d0,u0,d1,u1,d2,u2,d3,u3,d4,u4
    const float* hs = (const float*)d_in[0];
    const float* bd = (const float*)d_in[1];
    const float* bu = (const float*)d_in[2];
    const float* d0 = (const float*)d_in[3];
    const float* u0 = (const float*)d_in[4];
    const float* d1 = (const float*)d_in[5];
    const float* u1 = (const float*)d_in[6];
    const float* d2 = (const float*)d_in[7];
    const float* u2 = (const float*)d_in[8];
    const float* d3 = (const float*)d_in[9];
    const float* u3 = (const float*)d_in[10];
    const float* d4 = (const float*)d_in[11];
    const float* u4 = (const float*)d_in[12];

    unsigned short* wdFrag = (unsigned short*)d_ws;            // 49152 bf16
    unsigned short* wuFrag = wdFrag + 49152;                   // 49152 bf16

    tt_build_frags<<<384, 256, 0, stream>>>(d0, d1, d2, d3, d4,
                                            u0, u1, u2, u3, u4,
                                            wdFrag, wuFrag);

    // 256 persistent blocks (1/CU), 512 threads, 16 tiles of 8 rows each
    adapter_fused<<<256, 512, 0, stream>>>(hs, bd, bu, wdFrag, wuFrag,
                                           (float*)d_out);
}